// Round 7
// baseline (326.541 us; speedup 1.0000x reference)
//
#include <hip/hip_runtime.h>
#include <hip/hip_bf16.h>

#define HW 4096
#define CC 256
#define NBATCH 8
#define EPSF 1e-6f

typedef __attribute__((ext_vector_type(4))) float floatx4;
typedef long long llong;

// async global->LDS, 16B per lane (lds dst = uniform base + lane*16)
#define GLDS(g, l) __builtin_amdgcn_global_load_lds( \
    (const __attribute__((address_space(1))) void*)(const void*)(g), \
    (__attribute__((address_space(3))) void*)(void*)(l), 16, 0, 0)

// monotone float <-> unsigned key (order-preserving)
__device__ __forceinline__ unsigned fkey(float f){
    unsigned u = __float_as_uint(f);
    return (u & 0x80000000u) ? ~u : (u | 0x80000000u);
}
__device__ __forceinline__ float fdec(unsigned k){
    unsigned u = (k & 0x80000000u) ? (k ^ 0x80000000u) : ~k;
    return __uint_as_float(u);
}
__device__ __forceinline__ unsigned short f2bf(float f){
    unsigned u = __float_as_uint(f);
    u += 0x7FFFu + ((u >> 16) & 1);
    return (unsigned short)(u >> 16);
}

// ---------------- kernel 1: per-channel mean of y ----------------
__global__ __launch_bounds__(256) void kmean(const float* __restrict__ y,
                                             float* __restrict__ ymu){
    const int c = blockIdx.x;
    const int t = threadIdx.x;
    float s = 0.f;
    for(int n = 0; n < NBATCH; n++){
        const float* p = y + ((size_t)n*CC + c)*HW;
        for(int i = t; i < HW; i += 256) s += p[i];
    }
    __shared__ float red[256];
    red[t] = s; __syncthreads();
    for(int off = 128; off > 0; off >>= 1){
        if(t < off) red[t] += red[t+off];
        __syncthreads();
    }
    if(t == 0) ymu[c] = red[0] * (1.0f/((float)NBATCH*HW));
}

// ---- kernel 2: center, normalize over C, emit MFMA-fragment-major FP8 ----
// fp8 layout per batch (1 MB): addr(i,c) = (i>>4)*4096 + kt*512 + q*128 + (i&15)*8 + e
//   where c = kt*32 + q*8 + e. Fragment load = base + lane*8 (8B/lane).
// Also inits dmink/rowsum/colmaxk.
#define TROW 264
__global__ __launch_bounds__(256) void knorm(const float* __restrict__ x,
                                             const float* __restrict__ y,
                                             const float* __restrict__ ymu,
                                             unsigned char* __restrict__ xF,
                                             unsigned char* __restrict__ yF,
                                             unsigned* __restrict__ dmink,
                                             float* __restrict__ rowsum,
                                             unsigned* __restrict__ colmaxk){
    __shared__ __align__(16) unsigned short tile[64*TROW];
    __shared__ float invn[64];
    __shared__ float partial[4][64];
    __shared__ float smu[CC];
    const int t   = threadIdx.x;
    const int hw0 = blockIdx.x * 64;
    const int n   = blockIdx.y;
    if(t < 64){
        size_t g = (size_t)n*HW + hw0 + t;
        dmink[g] = 0xFFFFFFFFu;
        rowsum[g] = 0.f;
        colmaxk[g] = 0u;
    }
    for(int c = t; c < CC; c += 256) smu[c] = ymu[c];
    const int hwl = t & 63;
    const int cch = t >> 6;
    for(int which = 0; which < 2; which++){
        const float* __restrict__ src = which ? y : x;
        unsigned char* __restrict__ dst = which ? yF : xF;
        __syncthreads();
        float ss = 0.f;
        for(int cc = 0; cc < 64; cc++){
            int c = cch*64 + cc;
            float v = src[((size_t)n*CC + c)*HW + hw0 + hwl] - smu[c];
            ss += v*v;
            tile[hwl*TROW + c] = f2bf(v);
        }
        partial[cch][hwl] = ss;
        __syncthreads();
        if(t < 64){
            float s = partial[0][t]+partial[1][t]+partial[2][t]+partial[3][t];
            invn[t] = rsqrtf(s);
        }
        __syncthreads();
        size_t base = ((size_t)n << 20) + (size_t)(hw0 >> 4)*4096;
        #pragma unroll
        for(int v4 = 0; v4 < 4; v4++){
            int g  = v4*256 + t;           // 0..1023, unit = 16 fp8 (2 rows x 8 c)
            int it = g >> 8;
            int kt = (g >> 5) & 7;
            int qq = (g >> 3) & 3;
            int u  = g & 7;
            int r0 = it*16 + u*2;
            unsigned w[4];
            #pragma unroll
            for(int rr = 0; rr < 2; rr++){
                int r = r0 + rr;
                float inv = invn[r];
                const unsigned* lp = reinterpret_cast<const unsigned*>(&tile[r*TROW + kt*32 + qq*8]);
                float f[8];
                #pragma unroll
                for(int w2 = 0; w2 < 4; w2++){
                    unsigned uu = lp[w2];
                    f[2*w2]   = __uint_as_float((uu & 0xFFFFu) << 16) * inv;
                    f[2*w2+1] = __uint_as_float(uu & 0xFFFF0000u) * inv;
                }
                unsigned wa = 0, wb = 0;
                wa = __builtin_amdgcn_cvt_pk_fp8_f32(f[0], f[1], wa, false);
                wa = __builtin_amdgcn_cvt_pk_fp8_f32(f[2], f[3], wa, true);
                wb = __builtin_amdgcn_cvt_pk_fp8_f32(f[4], f[5], wb, false);
                wb = __builtin_amdgcn_cvt_pk_fp8_f32(f[6], f[7], wb, true);
                w[2*rr] = wa; w[2*rr+1] = wb;
            }
            uint4 ov; ov.x=w[0]; ov.y=w[1]; ov.z=w[2]; ov.w=w[3];
            *reinterpret_cast<uint4*>(dst + base + it*4096 + kt*512 + qq*128 + u*16) = ov;
        }
    }
}

// ---- sweep kernels: block = 512 i (4 waves x 128 i in regs) x 512-j slice.
// B staged via global_load_lds, double-buffered 4KB tiles (16 j x 256 c fp8).
// waves_per_eu(2,2): pin occupancy so the allocator keeps af[8][8] resident.
// MODE 0: dmin   1: rowsum of w   2: colmax of ccx (bb via LDS, sc in regs)
template<int MODE>
__global__ __launch_bounds__(256)
__attribute__((amdgpu_waves_per_eu(2, 2)))
void ksweep(const unsigned char* __restrict__ xF,
            const unsigned char* __restrict__ yF,
            unsigned* __restrict__ dmink,
            float* __restrict__ rowsum,
            unsigned* __restrict__ colmaxk){
    __shared__ __align__(16) unsigned char Bs[2][4096];
    __shared__ __align__(16) float bbS[4][128];
    const int t    = threadIdx.x;
    const int lane = t & 63;
    const int wave = t >> 6;
    const int q    = lane >> 4;
    const int l15  = lane & 15;
    const int bid  = blockIdx.x;
    const int n    = bid & 7;          // batch <-> XCD affinity
    const int rem  = bid >> 3;
    const int ip   = rem & 7;          // i-panel (512 rows)
    const int jq   = rem >> 3;         // j slice (512 cols)
    const size_t nb8 = (size_t)n << 20;
    const size_t nbw = (size_t)n * HW;
    const int iw   = ip*512 + wave*128;   // this wave's 128 rows
    const unsigned char* Ax = xF + nb8 + (size_t)(iw >> 4)*4096 + (size_t)lane*8;
    const unsigned char* Yb = yF + nb8 + (size_t)jq*131072;   // 512 j * 256 B

    llong af[8][8];
    #pragma unroll
    for(int ti = 0; ti < 8; ti++)
        #pragma unroll
        for(int kt = 0; kt < 8; kt++)
            af[ti][kt] = *reinterpret_cast<const llong*>(Ax + ti*4096 + kt*512);

    float sc[8][4];
    if(MODE >= 1){
        #pragma unroll
        for(int ti = 0; ti < 8; ti++)
            #pragma unroll
            for(int r = 0; r < 4; r++){
                size_t g = nbw + iw + ti*16 + q*4 + r;
                sc[ti][r] = 2.f / (fdec(dmink[g]) + EPSF);
            }
    }
    if(MODE == 2){
        // bb per row -> LDS (2 rows per lane)
        #pragma unroll
        for(int rr = 0; rr < 2; rr++){
            int row = lane*2 + rr;
            bbS[wave][row] = 2.f - __logf(rowsum[nbw + iw + row]);
        }
    }
    float racc[8][4];
    #pragma unroll
    for(int ti = 0; ti < 8; ti++)
        #pragma unroll
        for(int r = 0; r < 4; r++) racc[ti][r] = (MODE == 0) ? -3e38f : 0.f;

    // prologue: stage js=0 tile (4KB; one 1KB chunk per wave)
    GLDS(Yb + wave*1024 + lane*16, &Bs[0][wave*1024]);
    __syncthreads();

    #pragma unroll 1
    for(int js = 0; js < 32; js++){
        // stage next tile (js=31 overreads 4KB into slack; harmless)
        GLDS(Yb + (js+1)*4096 + wave*1024 + lane*16, &Bs[(js+1)&1][wave*1024]);
        const unsigned char* B = Bs[js&1];
        floatx4 acc[8];
        #pragma unroll
        for(int a = 0; a < 8; a++) acc[a] = (floatx4){0.f,0.f,0.f,0.f};
        #pragma unroll
        for(int kt = 0; kt < 8; kt++){
            llong b = *reinterpret_cast<const llong*>(B + kt*512 + lane*8);
            #pragma unroll
            for(int ti = 0; ti < 8; ti++)
                acc[ti] = __builtin_amdgcn_mfma_f32_16x16x32_fp8_fp8(
                              af[ti][kt], b, acc[ti], 0, 0, 0);
        }
        if(MODE == 0){
            #pragma unroll
            for(int ti = 0; ti < 8; ti++)
                #pragma unroll
                for(int r = 0; r < 4; r++)
                    racc[ti][r] = fmaxf(racc[ti][r], acc[ti][r]);
        } else if(MODE == 1){
            #pragma unroll
            for(int ti = 0; ti < 8; ti++)
                #pragma unroll
                for(int r = 0; r < 4; r++)
                    racc[ti][r] += __expf(fmaf(acc[ti][r] - 1.f, sc[ti][r], 2.f));
        } else {
            float a = -3e38f;
            #pragma unroll
            for(int ti = 0; ti < 8; ti++){
                const floatx4 bb4 = *reinterpret_cast<const floatx4*>(&bbS[wave][ti*16 + q*4]);
                #pragma unroll
                for(int r = 0; r < 4; r++)
                    a = fmaxf(a, fmaf(acc[ti][r] - 1.f, sc[ti][r], bb4[r]));
            }
            a = fmaxf(a, __shfl_xor(a, 16));
            a = fmaxf(a, __shfl_xor(a, 32));
            if(lane < 16)
                atomicMax(&colmaxk[nbw + jq*512 + js*16 + l15], fkey(__expf(a)));
        }
        __syncthreads();
    }

    if(MODE == 0){
        #pragma unroll
        for(int ti = 0; ti < 8; ti++)
            #pragma unroll
            for(int r = 0; r < 4; r++){
                float v = racc[ti][r];
                v = fmaxf(v, __shfl_xor(v, 1));
                v = fmaxf(v, __shfl_xor(v, 2));
                v = fmaxf(v, __shfl_xor(v, 4));
                v = fmaxf(v, __shfl_xor(v, 8));
                if(l15 == 0)
                    atomicMin(&dmink[nbw + iw + ti*16 + q*4 + r], fkey(1.f - v));
            }
    } else if(MODE == 1){
        #pragma unroll
        for(int ti = 0; ti < 8; ti++)
            #pragma unroll
            for(int r = 0; r < 4; r++){
                float v = racc[ti][r];
                v += __shfl_xor(v, 1);
                v += __shfl_xor(v, 2);
                v += __shfl_xor(v, 4);
                v += __shfl_xor(v, 8);
                if(l15 == 0)
                    atomicAdd(&rowsum[nbw + iw + ti*16 + q*4 + r], v);
            }
    }
}

// ---------------- final: loss = mean_n(-log(mean_j colmax + eps)) ----------
__global__ __launch_bounds__(256) void kfinal(const unsigned* __restrict__ colmaxk,
                                              float* __restrict__ out){
    __shared__ float red[256];
    const int t = threadIdx.x;
    float loss = 0.f;
    for(int n = 0; n < NBATCH; n++){
        float s = 0.f;
        for(int j = t; j < HW; j += 256) s += fdec(colmaxk[(size_t)n*HW + j]);
        red[t] = s; __syncthreads();
        for(int off = 128; off > 0; off >>= 1){
            if(t < off) red[t] += red[t+off];
            __syncthreads();
        }
        if(t == 0) loss += -logf(red[0]*(1.0f/HW) + EPSF);
        __syncthreads();
    }
    if(t == 0) out[0] = loss * (1.0f/NBATCH);
}

extern "C" void kernel_launch(void* const* d_in, const int* in_sizes, int n_in,
                              void* d_out, int out_size, void* d_ws, size_t ws_size,
                              hipStream_t stream){
    const float* x = (const float*)d_in[0];
    const float* y = (const float*)d_in[1];
    float* out = (float*)d_out;
    char* ws = (char*)d_ws;

    float* ymu = (float*)ws;
    size_t off = 1024;
    unsigned char* xF = (unsigned char*)(ws + off); off += (size_t)NBATCH << 20;
    unsigned char* yF = (unsigned char*)(ws + off); off += ((size_t)NBATCH << 20) + (512<<10); // tail-prefetch slack
    unsigned* dmink   = (unsigned*)(ws + off);      off += (size_t)NBATCH*HW*4;
    float* rowsum     = (float*)(ws + off);         off += (size_t)NBATCH*HW*4;
    unsigned* colmaxk = (unsigned*)(ws + off);      off += (size_t)NBATCH*HW*4;

    kmean<<<dim3(CC), dim3(256), 0, stream>>>(y, ymu);
    knorm<<<dim3(HW/64, NBATCH), dim3(256), 0, stream>>>(x, y, ymu, xF, yF,
                                                         dmink, rowsum, colmaxk);
    ksweep<0><<<dim3(512), dim3(256), 0, stream>>>(xF, yF, dmink, rowsum, colmaxk);
    ksweep<1><<<dim3(512), dim3(256), 0, stream>>>(xF, yF, dmink, rowsum, colmaxk);
    ksweep<2><<<dim3(512), dim3(256), 0, stream>>>(xF, yF, dmink, rowsum, colmaxk);
    kfinal<<<dim3(1), dim3(256), 0, stream>>>(colmaxk, out);
}

// Round 8
// 267.553 us; speedup vs baseline: 1.2205x; 1.2205x over previous
//
#include <hip/hip_runtime.h>
#include <hip/hip_bf16.h>

#define HW 4096
#define CC 256
#define NBATCH 8
#define EPSF 1e-6f

typedef __attribute__((ext_vector_type(4))) float floatx4;
typedef long long llong;

// async global->LDS, 16B per lane (lds dst = uniform base + lane*16)
#define GLDS(g, l) __builtin_amdgcn_global_load_lds( \
    (const __attribute__((address_space(1))) void*)(const void*)(g), \
    (__attribute__((address_space(3))) void*)(void*)(l), 16, 0, 0)

// monotone float <-> unsigned key (order-preserving)
__device__ __forceinline__ unsigned fkey(float f){
    unsigned u = __float_as_uint(f);
    return (u & 0x80000000u) ? ~u : (u | 0x80000000u);
}
__device__ __forceinline__ float fdec(unsigned k){
    unsigned u = (k & 0x80000000u) ? (k ^ 0x80000000u) : ~k;
    return __uint_as_float(u);
}
__device__ __forceinline__ unsigned short f2bf(float f){
    unsigned u = __float_as_uint(f);
    u += 0x7FFFu + ((u >> 16) & 1);
    return (unsigned short)(u >> 16);
}

// ---------------- kernel 1: per-channel mean of y ----------------
__global__ __launch_bounds__(256) void kmean(const float* __restrict__ y,
                                             float* __restrict__ ymu){
    const int c = blockIdx.x;
    const int t = threadIdx.x;
    float s = 0.f;
    for(int n = 0; n < NBATCH; n++){
        const float4* p = reinterpret_cast<const float4*>(y + ((size_t)n*CC + c)*HW);
        #pragma unroll
        for(int i = 0; i < 4; i++){
            float4 v = p[i*256 + t];
            s += (v.x + v.y) + (v.z + v.w);
        }
    }
    __shared__ float red[256];
    red[t] = s; __syncthreads();
    for(int off = 128; off > 0; off >>= 1){
        if(t < off) red[t] += red[t+off];
        __syncthreads();
    }
    if(t == 0) ymu[c] = red[0] * (1.0f/((float)NBATCH*HW));
}

// ---- kernel 2: center, normalize over C, emit MFMA-fragment-major FP8 ----
// fp8 layout per batch (1 MB): addr(i,c) = (i>>4)*4096 + kt*512 + q*128 + (i&15)*8 + e
//   where c = kt*32 + q*8 + e. Fragment load = base + lane*8 (8B/lane).
// Also inits dmink/rowsum/colmaxk.
#define TROW 264
__global__ __launch_bounds__(256) void knorm(const float* __restrict__ x,
                                             const float* __restrict__ y,
                                             const float* __restrict__ ymu,
                                             unsigned char* __restrict__ xF,
                                             unsigned char* __restrict__ yF,
                                             unsigned* __restrict__ dmink,
                                             float* __restrict__ rowsum,
                                             unsigned* __restrict__ colmaxk){
    __shared__ __align__(16) unsigned short tile[64*TROW];
    __shared__ float invn[64];
    __shared__ float partial[4][64];
    __shared__ float smu[CC];
    const int t   = threadIdx.x;
    const int hw0 = blockIdx.x * 64;
    const int n   = blockIdx.y;
    if(t < 64){
        size_t g = (size_t)n*HW + hw0 + t;
        dmink[g] = 0xFFFFFFFFu;
        rowsum[g] = 0.f;
        colmaxk[g] = 0u;
    }
    for(int c = t; c < CC; c += 256) smu[c] = ymu[c];
    const int hwl = t & 63;
    const int cch = t >> 6;
    for(int which = 0; which < 2; which++){
        const float* __restrict__ src = which ? y : x;
        unsigned char* __restrict__ dst = which ? yF : xF;
        __syncthreads();
        float ss = 0.f;
        for(int cc = 0; cc < 64; cc++){
            int c = cch*64 + cc;
            float v = src[((size_t)n*CC + c)*HW + hw0 + hwl] - smu[c];
            ss += v*v;
            tile[hwl*TROW + c] = f2bf(v);
        }
        partial[cch][hwl] = ss;
        __syncthreads();
        if(t < 64){
            float s = partial[0][t]+partial[1][t]+partial[2][t]+partial[3][t];
            invn[t] = rsqrtf(s);
        }
        __syncthreads();
        size_t base = ((size_t)n << 20) + (size_t)(hw0 >> 4)*4096;
        #pragma unroll
        for(int v4 = 0; v4 < 4; v4++){
            int g  = v4*256 + t;           // 0..1023, unit = 16 fp8 (2 rows x 8 c)
            int it = g >> 8;
            int kt = (g >> 5) & 7;
            int qq = (g >> 3) & 3;
            int u  = g & 7;
            int r0 = it*16 + u*2;
            unsigned w[4];
            #pragma unroll
            for(int rr = 0; rr < 2; rr++){
                int r = r0 + rr;
                float inv = invn[r];
                const unsigned* lp = reinterpret_cast<const unsigned*>(&tile[r*TROW + kt*32 + qq*8]);
                float f[8];
                #pragma unroll
                for(int w2 = 0; w2 < 4; w2++){
                    unsigned uu = lp[w2];
                    f[2*w2]   = __uint_as_float((uu & 0xFFFFu) << 16) * inv;
                    f[2*w2+1] = __uint_as_float(uu & 0xFFFF0000u) * inv;
                }
                unsigned wa = 0, wb = 0;
                wa = __builtin_amdgcn_cvt_pk_fp8_f32(f[0], f[1], wa, false);
                wa = __builtin_amdgcn_cvt_pk_fp8_f32(f[2], f[3], wa, true);
                wb = __builtin_amdgcn_cvt_pk_fp8_f32(f[4], f[5], wb, false);
                wb = __builtin_amdgcn_cvt_pk_fp8_f32(f[6], f[7], wb, true);
                w[2*rr] = wa; w[2*rr+1] = wb;
            }
            uint4 ov; ov.x=w[0]; ov.y=w[1]; ov.z=w[2]; ov.w=w[3];
            *reinterpret_cast<uint4*>(dst + base + it*4096 + kt*512 + qq*128 + u*16) = ov;
        }
    }
}

// ---- sweep kernels: block = 512 i (4 waves x 128 i in regs) x 512-j slice.
// B staged via global_load_lds in 16KB super-tiles (4 js-tiles of 16 j x 256 c),
// double-buffered; ONE barrier per 4 js so waves drift and MFMA/VALU phases
// overlap across waves.
// MODE 0: dmin   1: rowsum of w   2: colmax of ccx (bb via LDS, sc in regs)
template<int MODE>
__global__ __launch_bounds__(256, 2) void ksweep(
        const unsigned char* __restrict__ xF,
        const unsigned char* __restrict__ yF,
        unsigned* __restrict__ dmink,
        float* __restrict__ rowsum,
        unsigned* __restrict__ colmaxk){
    __shared__ __align__(16) unsigned char Bs[2][16384];
    __shared__ __align__(16) float bbS[4][128];
    const int t    = threadIdx.x;
    const int lane = t & 63;
    const int wave = t >> 6;
    const int q    = lane >> 4;
    const int l15  = lane & 15;
    const int bid  = blockIdx.x;
    const int n    = bid & 7;          // batch <-> XCD affinity
    const int rem  = bid >> 3;
    const int ip   = rem & 7;          // i-panel (512 rows)
    const int jq   = rem >> 3;         // j slice (512 cols)
    const size_t nb8 = (size_t)n << 20;
    const size_t nbw = (size_t)n * HW;
    const int iw   = ip*512 + wave*128;   // this wave's 128 rows
    const unsigned char* Ax = xF + nb8 + (size_t)(iw >> 4)*4096 + (size_t)lane*8;
    const unsigned char* Yb = yF + nb8 + (size_t)jq*131072;   // 512 j * 256 B

    llong af[8][8];
    #pragma unroll
    for(int ti = 0; ti < 8; ti++)
        #pragma unroll
        for(int kt = 0; kt < 8; kt++)
            af[ti][kt] = *reinterpret_cast<const llong*>(Ax + ti*4096 + kt*512);

    float sc[8][4];
    if(MODE >= 1){
        #pragma unroll
        for(int ti = 0; ti < 8; ti++)
            #pragma unroll
            for(int r = 0; r < 4; r++){
                size_t g = nbw + iw + ti*16 + q*4 + r;
                sc[ti][r] = 2.f / (fdec(dmink[g]) + EPSF);
            }
    }
    if(MODE == 2){
        // bb per row -> wave-private LDS (2 rows per lane, same-wave reads only)
        #pragma unroll
        for(int rr = 0; rr < 2; rr++){
            int row = lane*2 + rr;
            bbS[wave][row] = 2.f - __logf(rowsum[nbw + iw + row]);
        }
    }
    float racc[8][4];
    #pragma unroll
    for(int ti = 0; ti < 8; ti++)
        #pragma unroll
        for(int r = 0; r < 4; r++) racc[ti][r] = (MODE == 0) ? -3e38f : 0.f;

    // prologue: stage super-tile 0 (16KB; 4KB per wave = 4 x 1KB chunks)
    #pragma unroll
    for(int p = 0; p < 4; p++){
        int c = wave*4 + p;
        GLDS(Yb + c*1024 + (size_t)lane*16, &Bs[0][c*1024]);
    }
    __syncthreads();

    #pragma unroll 1
    for(int ss = 0; ss < 8; ss++){
        // stage next super-tile (ss=7 overreads 16KB into slack; harmless)
        {
            const unsigned char* src = Yb + (size_t)(ss+1)*16384;
            unsigned char* dstb = Bs[(ss+1)&1];
            #pragma unroll
            for(int p = 0; p < 4; p++){
                int c = wave*4 + p;
                GLDS(src + c*1024 + (size_t)lane*16, &dstb[c*1024]);
            }
        }
        #pragma unroll 1
        for(int u = 0; u < 4; u++){
            const unsigned char* B = &Bs[ss&1][u*4096];
            const int js = ss*4 + u;
            floatx4 acc[8];
            #pragma unroll
            for(int a = 0; a < 8; a++) acc[a] = (floatx4){0.f,0.f,0.f,0.f};
            #pragma unroll
            for(int kt = 0; kt < 8; kt++){
                llong b = *reinterpret_cast<const llong*>(B + kt*512 + lane*8);
                #pragma unroll
                for(int ti = 0; ti < 8; ti++)
                    acc[ti] = __builtin_amdgcn_mfma_f32_16x16x32_fp8_fp8(
                                  af[ti][kt], b, acc[ti], 0, 0, 0);
            }
            if(MODE == 0){
                #pragma unroll
                for(int ti = 0; ti < 8; ti++)
                    #pragma unroll
                    for(int r = 0; r < 4; r++)
                        racc[ti][r] = fmaxf(racc[ti][r], acc[ti][r]);
            } else if(MODE == 1){
                #pragma unroll
                for(int ti = 0; ti < 8; ti++)
                    #pragma unroll
                    for(int r = 0; r < 4; r++)
                        racc[ti][r] += __expf(fmaf(acc[ti][r] - 1.f, sc[ti][r], 2.f));
            } else {
                float a = -3e38f;
                #pragma unroll
                for(int ti = 0; ti < 8; ti++){
                    const floatx4 bb4 = *reinterpret_cast<const floatx4*>(&bbS[wave][ti*16 + q*4]);
                    #pragma unroll
                    for(int r = 0; r < 4; r++)
                        a = fmaxf(a, fmaf(acc[ti][r] - 1.f, sc[ti][r], bb4[r]));
                }
                a = fmaxf(a, __shfl_xor(a, 16));
                a = fmaxf(a, __shfl_xor(a, 32));
                if(lane < 16)
                    atomicMax(&colmaxk[nbw + jq*512 + js*16 + l15], fkey(__expf(a)));
            }
        }
        __syncthreads();
    }

    if(MODE == 0){
        #pragma unroll
        for(int ti = 0; ti < 8; ti++)
            #pragma unroll
            for(int r = 0; r < 4; r++){
                float v = racc[ti][r];
                v = fmaxf(v, __shfl_xor(v, 1));
                v = fmaxf(v, __shfl_xor(v, 2));
                v = fmaxf(v, __shfl_xor(v, 4));
                v = fmaxf(v, __shfl_xor(v, 8));
                if(l15 == 0)
                    atomicMin(&dmink[nbw + iw + ti*16 + q*4 + r], fkey(1.f - v));
            }
    } else if(MODE == 1){
        #pragma unroll
        for(int ti = 0; ti < 8; ti++)
            #pragma unroll
            for(int r = 0; r < 4; r++){
                float v = racc[ti][r];
                v += __shfl_xor(v, 1);
                v += __shfl_xor(v, 2);
                v += __shfl_xor(v, 4);
                v += __shfl_xor(v, 8);
                if(l15 == 0)
                    atomicAdd(&rowsum[nbw + iw + ti*16 + q*4 + r], v);
            }
    }
}

// ---------------- final: per-batch partial, then tiny reduce ----------------
__global__ __launch_bounds__(256) void kpart(const unsigned* __restrict__ colmaxk,
                                             float* __restrict__ part){
    __shared__ float red[256];
    const int t = threadIdx.x;
    const int n = blockIdx.x;
    float s = 0.f;
    for(int j = t; j < HW; j += 256) s += fdec(colmaxk[(size_t)n*HW + j]);
    red[t] = s; __syncthreads();
    for(int off = 128; off > 0; off >>= 1){
        if(t < off) red[t] += red[t+off];
        __syncthreads();
    }
    if(t == 0) part[n] = -logf(red[0]*(1.0f/HW) + EPSF);
}

__global__ __launch_bounds__(64) void kfin(const float* __restrict__ part,
                                           float* __restrict__ out){
    const int t = threadIdx.x;
    float v = (t < NBATCH) ? part[t] : 0.f;
    v += __shfl_xor(v, 1);
    v += __shfl_xor(v, 2);
    v += __shfl_xor(v, 4);
    if(t == 0) out[0] = v * (1.0f/NBATCH);
}

extern "C" void kernel_launch(void* const* d_in, const int* in_sizes, int n_in,
                              void* d_out, int out_size, void* d_ws, size_t ws_size,
                              hipStream_t stream){
    const float* x = (const float*)d_in[0];
    const float* y = (const float*)d_in[1];
    float* out = (float*)d_out;
    char* ws = (char*)d_ws;

    float* ymu = (float*)ws;
    size_t off = 1024;
    unsigned char* xF = (unsigned char*)(ws + off); off += (size_t)NBATCH << 20;
    unsigned char* yF = (unsigned char*)(ws + off); off += ((size_t)NBATCH << 20) + (512<<10); // tail-prefetch slack
    unsigned* dmink   = (unsigned*)(ws + off);      off += (size_t)NBATCH*HW*4;
    float* rowsum     = (float*)(ws + off);         off += (size_t)NBATCH*HW*4;
    unsigned* colmaxk = (unsigned*)(ws + off);      off += (size_t)NBATCH*HW*4;
    float* part       = (float*)(ws + off);         off += 64;

    kmean<<<dim3(CC), dim3(256), 0, stream>>>(y, ymu);
    knorm<<<dim3(HW/64, NBATCH), dim3(256), 0, stream>>>(x, y, ymu, xF, yF,
                                                         dmink, rowsum, colmaxk);
    ksweep<0><<<dim3(512), dim3(256), 0, stream>>>(xF, yF, dmink, rowsum, colmaxk);
    ksweep<1><<<dim3(512), dim3(256), 0, stream>>>(xF, yF, dmink, rowsum, colmaxk);
    ksweep<2><<<dim3(512), dim3(256), 0, stream>>>(xF, yF, dmink, rowsum, colmaxk);
    kpart<<<dim3(NBATCH), dim3(256), 0, stream>>>(colmaxk, part);
    kfin<<<dim3(1), dim3(64), 0, stream>>>(part, out);
}

// Round 9
// 233.274 us; speedup vs baseline: 1.3998x; 1.1469x over previous
//
#include <hip/hip_runtime.h>
#include <hip/hip_bf16.h>

#define HW 4096
#define CC 256
#define NBATCH 8
#define EPSF 1e-6f
#define SCL1 0x7F7F7F7F   // E8M0 exponent 127 -> scale 1.0 in all bytes

typedef __attribute__((ext_vector_type(4))) float floatx4;
typedef __attribute__((ext_vector_type(8))) int intx8;
typedef long long llong;

// async global->LDS, 16B per lane (lds dst = uniform base + lane*16)
#define GLDS(g, l) __builtin_amdgcn_global_load_lds( \
    (const __attribute__((address_space(1))) void*)(const void*)(g), \
    (__attribute__((address_space(3))) void*)(void*)(l), 16, 0, 0)

// monotone float <-> unsigned key (order-preserving)
__device__ __forceinline__ unsigned fkey(float f){
    unsigned u = __float_as_uint(f);
    return (u & 0x80000000u) ? ~u : (u | 0x80000000u);
}
__device__ __forceinline__ float fdec(unsigned k){
    unsigned u = (k & 0x80000000u) ? (k ^ 0x80000000u) : ~k;
    return __uint_as_float(u);
}
__device__ __forceinline__ unsigned short f2bf(float f){
    unsigned u = __float_as_uint(f);
    u += 0x7FFFu + ((u >> 16) & 1);
    return (unsigned short)(u >> 16);
}

// ---------------- kernel 1: per-channel mean of y ----------------
__global__ __launch_bounds__(256) void kmean(const float* __restrict__ y,
                                             float* __restrict__ ymu){
    const int c = blockIdx.x;
    const int t = threadIdx.x;
    float s = 0.f;
    for(int n = 0; n < NBATCH; n++){
        const float4* p = reinterpret_cast<const float4*>(y + ((size_t)n*CC + c)*HW);
        #pragma unroll
        for(int i = 0; i < 4; i++){
            float4 v = p[i*256 + t];
            s += (v.x + v.y) + (v.z + v.w);
        }
    }
    __shared__ float red[256];
    red[t] = s; __syncthreads();
    for(int off = 128; off > 0; off >>= 1){
        if(t < off) red[t] += red[t+off];
        __syncthreads();
    }
    if(t == 0) ymu[c] = red[0] * (1.0f/((float)NBATCH*HW));
}

// ---- kernel 2: center, normalize over C, emit MFMA-fragment-major FP8 ----
// fp8 layout per batch (1 MB): addr(i,c) = (i>>4)*4096 + kt*512 + q*128 + (i&15)*8 + e
//   where c = kt*32 + q*8 + e. Also inits dmink/rowsum/colmaxk.
#define TROW 264
__global__ __launch_bounds__(256) void knorm(const float* __restrict__ x,
                                             const float* __restrict__ y,
                                             const float* __restrict__ ymu,
                                             unsigned char* __restrict__ xF,
                                             unsigned char* __restrict__ yF,
                                             unsigned* __restrict__ dmink,
                                             float* __restrict__ rowsum,
                                             unsigned* __restrict__ colmaxk){
    __shared__ __align__(16) unsigned short tile[64*TROW];
    __shared__ float invn[64];
    __shared__ float partial[4][64];
    __shared__ float smu[CC];
    const int t   = threadIdx.x;
    const int hw0 = blockIdx.x * 64;
    const int n   = blockIdx.y;
    if(t < 64){
        size_t g = (size_t)n*HW + hw0 + t;
        dmink[g] = 0xFFFFFFFFu;
        rowsum[g] = 0.f;
        colmaxk[g] = 0u;
    }
    for(int c = t; c < CC; c += 256) smu[c] = ymu[c];
    const int hwl = t & 63;
    const int cch = t >> 6;
    for(int which = 0; which < 2; which++){
        const float* __restrict__ src = which ? y : x;
        unsigned char* __restrict__ dst = which ? yF : xF;
        __syncthreads();
        float ss = 0.f;
        for(int cc = 0; cc < 64; cc++){
            int c = cch*64 + cc;
            float v = src[((size_t)n*CC + c)*HW + hw0 + hwl] - smu[c];
            ss += v*v;
            tile[hwl*TROW + c] = f2bf(v);
        }
        partial[cch][hwl] = ss;
        __syncthreads();
        if(t < 64){
            float s = partial[0][t]+partial[1][t]+partial[2][t]+partial[3][t];
            invn[t] = rsqrtf(s);
        }
        __syncthreads();
        size_t base = ((size_t)n << 20) + (size_t)(hw0 >> 4)*4096;
        #pragma unroll
        for(int v4 = 0; v4 < 4; v4++){
            int g  = v4*256 + t;           // 0..1023, unit = 16 fp8 (2 rows x 8 c)
            int it = g >> 8;
            int kt = (g >> 5) & 7;
            int qq = (g >> 3) & 3;
            int u  = g & 7;
            int r0 = it*16 + u*2;
            unsigned w[4];
            #pragma unroll
            for(int rr = 0; rr < 2; rr++){
                int r = r0 + rr;
                float inv = invn[r];
                const unsigned* lp = reinterpret_cast<const unsigned*>(&tile[r*TROW + kt*32 + qq*8]);
                float f[8];
                #pragma unroll
                for(int w2 = 0; w2 < 4; w2++){
                    unsigned uu = lp[w2];
                    f[2*w2]   = __uint_as_float((uu & 0xFFFFu) << 16) * inv;
                    f[2*w2+1] = __uint_as_float(uu & 0xFFFF0000u) * inv;
                }
                unsigned wa = 0, wb = 0;
                wa = __builtin_amdgcn_cvt_pk_fp8_f32(f[0], f[1], wa, false);
                wa = __builtin_amdgcn_cvt_pk_fp8_f32(f[2], f[3], wa, true);
                wb = __builtin_amdgcn_cvt_pk_fp8_f32(f[4], f[5], wb, false);
                wb = __builtin_amdgcn_cvt_pk_fp8_f32(f[6], f[7], wb, true);
                w[2*rr] = wa; w[2*rr+1] = wb;
            }
            uint4 ov; ov.x=w[0]; ov.y=w[1]; ov.z=w[2]; ov.w=w[3];
            *reinterpret_cast<uint4*>(dst + base + it*4096 + kt*512 + qq*128 + u*16) = ov;
        }
    }
}

// ---- sweep kernels: block = 512 i (4 waves x 128 i in regs) x 512-j slice.
// MX-scaled MFMA 16x16x128 fp8 (unit scales) = 2x rate of plain fp8.
// Per-lane fragment (K=128): row m = lane&15, k = (lane>>4)*32 + [0..32)
//   = 4 x 8B pieces at (kt=q or 4+q), q'=0..3 in the fragment-major store.
// B staged via global_load_lds in 16KB super-tiles (4 js-tiles of 16 j),
// double-buffered, one barrier per 4 js.
// MODE 0: dmin   1: rowsum of w (sc via LDS)   2: colmax (sc+bb via LDS)
union U8 { intx8 v; llong d[4]; };

template<int MODE>
__global__ __launch_bounds__(256, 2) void ksweep(
        const unsigned char* __restrict__ xF,
        const unsigned char* __restrict__ yF,
        unsigned* __restrict__ dmink,
        float* __restrict__ rowsum,
        unsigned* __restrict__ colmaxk){
    __shared__ __align__(16) unsigned char Bs[2][16384];
    __shared__ __align__(16) float scS[4][128];
    __shared__ __align__(16) float bbS[4][128];
    const int t    = threadIdx.x;
    const int lane = t & 63;
    const int wave = t >> 6;
    const int q    = lane >> 4;
    const int l15  = lane & 15;
    const int bid  = blockIdx.x;
    const int n    = bid & 7;          // batch <-> XCD affinity
    const int rem  = bid >> 3;
    const int ip   = rem & 7;          // i-panel (512 rows)
    const int jq   = rem >> 3;         // j slice (512 cols)
    const size_t nb8 = (size_t)n << 20;
    const size_t nbw = (size_t)n * HW;
    const int iw   = ip*512 + wave*128;   // this wave's 128 rows
    const unsigned char* Ax = xF + nb8 + (size_t)(iw >> 4)*4096 + q*512 + l15*8;
    const unsigned char* Yb = yF + nb8 + (size_t)jq*131072;   // 512 j * 256 B

    // A fragments: af0 = k[q*32..q*32+32), af1 = k[128+q*32..+32)
    U8 af0[8], af1[8];
    #pragma unroll
    for(int ti = 0; ti < 8; ti++)
        #pragma unroll
        for(int qq = 0; qq < 4; qq++){
            af0[ti].d[qq] = *reinterpret_cast<const llong*>(Ax + ti*4096 + qq*128);
            af1[ti].d[qq] = *reinterpret_cast<const llong*>(Ax + ti*4096 + 2048 + qq*128);
        }

    if(MODE >= 1){
        // per-row sc (and bb) -> wave-private broadcast LDS (2 rows per lane)
        #pragma unroll
        for(int rr = 0; rr < 2; rr++){
            int row = lane*2 + rr;
            size_t g = nbw + iw + row;
            scS[wave][row] = 2.f / (fdec(dmink[g]) + EPSF);
            if(MODE == 2) bbS[wave][row] = 2.f - __logf(rowsum[g]);
        }
    }
    float racc[8][4];
    #pragma unroll
    for(int ti = 0; ti < 8; ti++)
        #pragma unroll
        for(int r = 0; r < 4; r++) racc[ti][r] = (MODE == 0) ? -3e38f : 0.f;

    // prologue: stage super-tile 0 (16KB; 4KB per wave = 4 x 1KB chunks)
    #pragma unroll
    for(int p = 0; p < 4; p++){
        int c = wave*4 + p;
        GLDS(Yb + c*1024 + (size_t)lane*16, &Bs[0][c*1024]);
    }
    __syncthreads();

    #pragma unroll 1
    for(int ss = 0; ss < 8; ss++){
        // stage next super-tile (ss=7 overreads 16KB into slack; harmless)
        {
            const unsigned char* src = Yb + (size_t)(ss+1)*16384;
            unsigned char* dstb = Bs[(ss+1)&1];
            #pragma unroll
            for(int p = 0; p < 4; p++){
                int c = wave*4 + p;
                GLDS(src + c*1024 + (size_t)lane*16, &dstb[c*1024]);
            }
        }
        #pragma unroll 1
        for(int u = 0; u < 4; u++){
            const unsigned char* Bq = &Bs[ss&1][u*4096] + q*512 + l15*8;
            const int js = ss*4 + u;
            U8 b0, b1;
            #pragma unroll
            for(int qq = 0; qq < 4; qq++){
                b0.d[qq] = *reinterpret_cast<const llong*>(Bq + qq*128);
                b1.d[qq] = *reinterpret_cast<const llong*>(Bq + 2048 + qq*128);
            }
            floatx4 acc[8];
            #pragma unroll
            for(int a = 0; a < 8; a++) acc[a] = (floatx4){0.f,0.f,0.f,0.f};
            #pragma unroll
            for(int ti = 0; ti < 8; ti++){
                acc[ti] = __builtin_amdgcn_mfma_scale_f32_16x16x128_f8f6f4(
                              af0[ti].v, b0.v, acc[ti], 0, 0, 0, SCL1, 0, SCL1);
                acc[ti] = __builtin_amdgcn_mfma_scale_f32_16x16x128_f8f6f4(
                              af1[ti].v, b1.v, acc[ti], 0, 0, 0, SCL1, 0, SCL1);
            }
            if(MODE == 0){
                #pragma unroll
                for(int ti = 0; ti < 8; ti++)
                    #pragma unroll
                    for(int r = 0; r < 4; r++)
                        racc[ti][r] = fmaxf(racc[ti][r], acc[ti][r]);
            } else if(MODE == 1){
                #pragma unroll
                for(int ti = 0; ti < 8; ti++){
                    const floatx4 sc4 = *reinterpret_cast<const floatx4*>(&scS[wave][ti*16 + q*4]);
                    #pragma unroll
                    for(int r = 0; r < 4; r++)
                        racc[ti][r] += __expf(fmaf(acc[ti][r] - 1.f, sc4[r], 2.f));
                }
            } else {
                float a = -3e38f;
                #pragma unroll
                for(int ti = 0; ti < 8; ti++){
                    const floatx4 sc4 = *reinterpret_cast<const floatx4*>(&scS[wave][ti*16 + q*4]);
                    const floatx4 bb4 = *reinterpret_cast<const floatx4*>(&bbS[wave][ti*16 + q*4]);
                    #pragma unroll
                    for(int r = 0; r < 4; r++)
                        a = fmaxf(a, fmaf(acc[ti][r] - 1.f, sc4[r], bb4[r]));
                }
                a = fmaxf(a, __shfl_xor(a, 16));
                a = fmaxf(a, __shfl_xor(a, 32));
                if(lane < 16)
                    atomicMax(&colmaxk[nbw + jq*512 + js*16 + l15], fkey(__expf(a)));
            }
        }
        __syncthreads();
    }

    if(MODE == 0){
        #pragma unroll
        for(int ti = 0; ti < 8; ti++)
            #pragma unroll
            for(int r = 0; r < 4; r++){
                float v = racc[ti][r];
                v = fmaxf(v, __shfl_xor(v, 1));
                v = fmaxf(v, __shfl_xor(v, 2));
                v = fmaxf(v, __shfl_xor(v, 4));
                v = fmaxf(v, __shfl_xor(v, 8));
                if(l15 == 0)
                    atomicMin(&dmink[nbw + iw + ti*16 + q*4 + r], fkey(1.f - v));
            }
    } else if(MODE == 1){
        #pragma unroll
        for(int ti = 0; ti < 8; ti++)
            #pragma unroll
            for(int r = 0; r < 4; r++){
                float v = racc[ti][r];
                v += __shfl_xor(v, 1);
                v += __shfl_xor(v, 2);
                v += __shfl_xor(v, 4);
                v += __shfl_xor(v, 8);
                if(l15 == 0)
                    atomicAdd(&rowsum[nbw + iw + ti*16 + q*4 + r], v);
            }
    }
}

// ---------------- final: per-batch partial, then tiny reduce ----------------
__global__ __launch_bounds__(256) void kpart(const unsigned* __restrict__ colmaxk,
                                             float* __restrict__ part){
    __shared__ float red[256];
    const int t = threadIdx.x;
    const int n = blockIdx.x;
    float s = 0.f;
    for(int j = t; j < HW; j += 256) s += fdec(colmaxk[(size_t)n*HW + j]);
    red[t] = s; __syncthreads();
    for(int off = 128; off > 0; off >>= 1){
        if(t < off) red[t] += red[t+off];
        __syncthreads();
    }
    if(t == 0) part[n] = -logf(red[0]*(1.0f/HW) + EPSF);
}

__global__ __launch_bounds__(64) void kfin(const float* __restrict__ part,
                                           float* __restrict__ out){
    const int t = threadIdx.x;
    float v = (t < NBATCH) ? part[t] : 0.f;
    v += __shfl_xor(v, 1);
    v += __shfl_xor(v, 2);
    v += __shfl_xor(v, 4);
    if(t == 0) out[0] = v * (1.0f/NBATCH);
}

extern "C" void kernel_launch(void* const* d_in, const int* in_sizes, int n_in,
                              void* d_out, int out_size, void* d_ws, size_t ws_size,
                              hipStream_t stream){
    const float* x = (const float*)d_in[0];
    const float* y = (const float*)d_in[1];
    float* out = (float*)d_out;
    char* ws = (char*)d_ws;

    float* ymu = (float*)ws;
    size_t off = 1024;
    unsigned char* xF = (unsigned char*)(ws + off); off += (size_t)NBATCH << 20;
    unsigned char* yF = (unsigned char*)(ws + off); off += ((size_t)NBATCH << 20) + (512<<10); // tail-prefetch slack
    unsigned* dmink   = (unsigned*)(ws + off);      off += (size_t)NBATCH*HW*4;
    float* rowsum     = (float*)(ws + off);         off += (size_t)NBATCH*HW*4;
    unsigned* colmaxk = (unsigned*)(ws + off);      off += (size_t)NBATCH*HW*4;
    float* part       = (float*)(ws + off);         off += 64;

    kmean<<<dim3(CC), dim3(256), 0, stream>>>(y, ymu);
    knorm<<<dim3(HW/64, NBATCH), dim3(256), 0, stream>>>(x, y, ymu, xF, yF,
                                                         dmink, rowsum, colmaxk);
    ksweep<0><<<dim3(512), dim3(256), 0, stream>>>(xF, yF, dmink, rowsum, colmaxk);
    ksweep<1><<<dim3(512), dim3(256), 0, stream>>>(xF, yF, dmink, rowsum, colmaxk);
    ksweep<2><<<dim3(512), dim3(256), 0, stream>>>(xF, yF, dmink, rowsum, colmaxk);
    kpart<<<dim3(NBATCH), dim3(256), 0, stream>>>(colmaxk, part);
    kfin<<<dim3(1), dim3(64), 0, stream>>>(part, out);
}